// Round 8
// baseline (628.019 us; speedup 1.0000x reference)
//
#include <hip/hip_runtime.h>
#include <cstdint>
#include <cstddef>

// ---------------------------------------------------------------------------
// SwitchBack int8 MLP: x -> rowquant -> i8GEMM(+bias+gelu) -> rowquant ->
//                      i8GEMM(+bias) -> out
// GEMM: 256x256 tile, BK=64, 8 waves, 4-deep LDS pipeline (prefetch lead 5-6
// phases, vmcnt(8) once/tile), T2 swizzle (2-way free), T5 setprio, T1 XCD.
// mfma_i32_16x16x64_i8 == exact integer arithmetic == reference fp32 matmul.
// ---------------------------------------------------------------------------

typedef int v4i __attribute__((ext_vector_type(4)));

#define AS1 __attribute__((address_space(1)))
#define AS3 __attribute__((address_space(3)))

#define WAIT_LGKM(N) asm volatile("s_waitcnt lgkmcnt(" #N ")" ::: "memory")
#define WAIT_VM(N)   asm volatile("s_waitcnt vmcnt(" #N ")" ::: "memory")
#define SBAR() __builtin_amdgcn_s_barrier()
#define SFENCE() __builtin_amdgcn_sched_barrier(0)

__device__ __forceinline__ void gload_lds16(const void* g, void* l) {
    __builtin_amdgcn_global_load_lds((const AS1 void*)g, (AS3 void*)l, 16, 0, 0);
}

__device__ __forceinline__ float absmax4(float4 v, float cur) {
    return fmaxf(cur, fmaxf(fmaxf(fabsf(v.x), fabsf(v.y)),
                            fmaxf(fabsf(v.z), fabsf(v.w))));
}

__device__ __forceinline__ int quant1(float x, float inv) {
    int q = (int)rintf(x * inv);
    return min(127, max(-127, q));
}

__device__ __forceinline__ uint32_t quant4(float4 v, float inv) {
    uint32_t b0 = (uint32_t)(uint8_t)(int8_t)quant1(v.x, inv);
    uint32_t b1 = (uint32_t)(uint8_t)(int8_t)quant1(v.y, inv);
    uint32_t b2 = (uint32_t)(uint8_t)(int8_t)quant1(v.z, inv);
    uint32_t b3 = (uint32_t)(uint8_t)(int8_t)quant1(v.w, inv);
    return b0 | (b1 << 8) | (b2 << 16) | (b3 << 24);
}

// ---------------- global absmax of a big f32 array ----------------
__global__ __launch_bounds__(256) void wabs_kernel(
    const float* __restrict__ W, int n4, float* __restrict__ out)
{
    int tid = blockIdx.x * 256 + threadIdx.x;
    int stride = gridDim.x * 256;
    const float4* W4 = (const float4*)W;
    float amax = 0.0f;
    for (int i = tid; i < n4; i += stride) amax = absmax4(W4[i], amax);
    #pragma unroll
    for (int off = 32; off >= 1; off >>= 1)
        amax = fmaxf(amax, __shfl_xor(amax, off));
    __shared__ float red[4];
    if ((threadIdx.x & 63) == 0) red[threadIdx.x >> 6] = amax;
    __syncthreads();
    if (threadIdx.x == 0) {
        amax = fmaxf(fmaxf(red[0], red[1]), fmaxf(red[2], red[3]));
        atomicMax((int*)out, __float_as_int(amax));  // nonneg floats: int order ok
    }
}

// ---------------- quantize whole tensor with global scale ----------------
__global__ __launch_bounds__(256) void wquant_kernel(
    const float* __restrict__ W, int n4, const float* __restrict__ s,
    uint32_t* __restrict__ Wq)
{
    float inv = 127.0f / s[0];
    int tid = blockIdx.x * 256 + threadIdx.x;
    int stride = gridDim.x * 256;
    const float4* W4 = (const float4*)W;
    for (int i = tid; i < n4; i += stride) Wq[i] = quant4(W4[i], inv);
}

// ---------------- per-row absmax + quantize (one block per row) ----------------
template<int CNT>
__global__ __launch_bounds__(256) void rowquant_kernel(
    const float* __restrict__ X, int8_t* __restrict__ Xq,
    float* __restrict__ rowAbs)
{
    const int row = blockIdx.x;
    const int t = threadIdx.x;
    const size_t cols = (size_t)CNT * 1024;
    const float4* Xr = (const float4*)(X + (size_t)row * cols);
    float4 vals[CNT];
    float amax = 0.0f;
    #pragma unroll
    for (int j = 0; j < CNT; j++) {
        vals[j] = Xr[j * 256 + t];
        amax = absmax4(vals[j], amax);
    }
    #pragma unroll
    for (int off = 32; off >= 1; off >>= 1)
        amax = fmaxf(amax, __shfl_xor(amax, off));
    __shared__ float red[4];
    if ((t & 63) == 0) red[t >> 6] = amax;
    __syncthreads();
    amax = fmaxf(fmaxf(red[0], red[1]), fmaxf(red[2], red[3]));
    if (t == 0) rowAbs[row] = amax;
    float inv = 127.0f / amax;
    uint32_t* out = (uint32_t*)(Xq + (size_t)row * cols);
    #pragma unroll
    for (int j = 0; j < CNT; j++) out[j * 256 + t] = quant4(vals[j], inv);
}

// ---------------- int8 GEMM, 256x256 tile, BK=64, 4-deep pipeline ----------
// A: [M,K] i8 row-major, B: [Ncols,K] i8 row-major. C[m,n] = sum A[m,k]B[n,k].
// 512 threads = 8 waves (2 wr x 4 wc), each wave owns 128x64 of C.
// LDS 128KB: A [4buf][256][64], B [4buf][256][64].
// Swizzle: LDS row r, 16B-slot s (0..3) holds global slot s^((r>>1)&3);
// gload_lds dest linear, SOURCE pre-swizzled (rule #21). Fragment reads are
// 2-way bank aliased (free, m136).
// Per tile T (buf=T&3), 2 phases; stage tile T+3 (A in PA, B in PB):
//   PA: ds a0(m0-3)+b(4)=8; stage A(T+3); bar; lgkm0; 16 MFMA; bar
//   PB: ds a1(m4-7)=4;      stage B(T+3); bar; lgkm0; 16 MFMA; vmcnt(8); bar
// vmcnt(8) drains tile T+1 (issued at T-2 -> 5-6 phases in flight ~ 900 cyc).
template<int GELU>
__global__ __launch_bounds__(512, 2) void gemm8_i8(
    const int8_t* __restrict__ A, const int8_t* __restrict__ B,
    int K, int Ncols, int nbx,
    const float* __restrict__ rowScale, const float* __restrict__ wScale,
    const float* __restrict__ bias, float* __restrict__ Cout)
{
    extern __shared__ int8_t lds[];
    int8_t* AsB = lds;             // [4][256][64] = 64KB
    int8_t* BsB = lds + 65536;     // [4][256][64] = 64KB

    // T1: XCD-aware swizzle (all launches have gridDim.x % 8 == 0)
    const int nwg = gridDim.x;
    const int bid = blockIdx.x;
    const int wg = (bid & 7) * (nwg >> 3) + (bid >> 3);
    const int bx = wg % nbx;
    const int by = wg / nbx;
    const int brow = by * 256;
    const int bcol = bx * 256;

    const int t = threadIdx.x;
    const int lane = t & 63;
    const int w = t >> 6;          // wave 0..7
    const int wr = w >> 2;         // 0..1 (A rows 128*wr)
    const int wc = w & 3;          // 0..3 (B rows 64*wc)
    const int llo = lane & 15;
    const int lhi = lane >> 4;     // k-slot 0..3

    const int8_t* gA = A + (size_t)brow * K;
    const int8_t* gB = B + (size_t)bcol * K;

    // staging: thread t writes LDS bytes [t*16,+16) (row t>>2, slot t&3) and
    // [+8192] (row +128). Source slot pre-swizzled: (t&3)^((t>>3)&3).
    const size_t srcOffBase = (size_t)(t >> 2) * K
                            + (size_t)(((t & 3) ^ ((t >> 3) & 3)) * 16);
    const int ldsDst = t * 16;

    // reader: fragment row r = base+m*16+llo (base mult of 16), want k-slot
    // lhi -> LDS slot lhi^((r>>1)&3) = lhi^((llo>>1)&3) (lane-constant byte).
    const int sA = ((lhi ^ ((llo >> 1) & 3)) << 4);
    const int aOff = (wr * 128 + llo) * 64 + sA;
    const int bOff = (wc * 64 + llo) * 64 + sA;

    const int NT = K >> 6;

    v4i acc[8][4] = {};

    // stage one operand-tile (256 rows x 64 cols) of K-tile srcTile
    auto stageA = [&](int srcTile) {
        const size_t gb = (size_t)srcTile * 64 + srcOffBase;
        int8_t* d = AsB + (srcTile & 3) * 16384 + ldsDst;
        gload_lds16(gA + gb, d);
        gload_lds16(gA + gb + (size_t)128 * K, d + 8192);
    };
    auto stageB = [&](int srcTile) {
        const size_t gb = (size_t)srcTile * 64 + srcOffBase;
        int8_t* d = BsB + (srcTile & 3) * 16384 + ldsDst;
        gload_lds16(gB + gb, d);
        gload_lds16(gB + gb + (size_t)128 * K, d + 8192);
    };

    // prologue: stage tiles 0,1,2 (12 loads); drain tile 0 (leave 8 in flight)
    stageA(0); stageB(0); stageA(1); stageB(1); stageA(2); stageB(2);
    WAIT_VM(8);
    SFENCE();
    SBAR();

    #define MFMA16(AV, BV, MOFF)                                            \
        __builtin_amdgcn_s_setprio(1);                                      \
        _Pragma("unroll")                                                   \
        for (int m = 0; m < 4; m++)                                         \
            _Pragma("unroll")                                               \
            for (int n = 0; n < 4; n++)                                     \
                acc[MOFF + m][n] = __builtin_amdgcn_mfma_i32_16x16x64_i8(   \
                    AV[m], BV[n], acc[MOFF + m][n], 0, 0, 0);               \
        __builtin_amdgcn_s_setprio(0);

    for (int T = 0; T < NT; ++T) {
        const int buf = T & 3;
        const int8_t* Ab = AsB + buf * 16384;
        const int8_t* Bb = BsB + buf * 16384;
        const int ts = (T + 3 < NT) ? T + 3 : NT - 1;  // clamped: lands in
                                                       // unread buffers, keeps
                                                       // issue counts uniform
        v4i a0[4], a1[4], bb[4];

        // ---- PA ---- (8 ds_reads; stage A(T+3); MFMA m0-3)
        #pragma unroll
        for (int m = 0; m < 4; m++) a0[m] = *(const v4i*)(Ab + aOff + m * 1024);
        #pragma unroll
        for (int n = 0; n < 4; n++) bb[n] = *(const v4i*)(Bb + bOff + n * 1024);
        stageA(ts);
        SBAR();
        WAIT_LGKM(0);
        SFENCE();
        MFMA16(a0, bb, 0)
        SBAR();

        // ---- PB ---- (4 ds_reads; stage B(T+3); MFMA m4-7; drain T+1)
        #pragma unroll
        for (int m = 0; m < 4; m++) a1[m] = *(const v4i*)(Ab + aOff + 4096 + m * 1024);
        stageB(ts);
        SBAR();
        WAIT_LGKM(0);
        SFENCE();
        MFMA16(a1, bb, 4)
        WAIT_VM(8);
        SFENCE();
        SBAR();
    }
    #undef MFMA16

    WAIT_VM(0);  // drain clamped tail stages before exit

    // epilogue: C/D layout col=lane&15, row=(lane>>4)*4+reg
    const float wsc = wScale[0] * (1.0f / (127.0f * 127.0f));
    #pragma unroll
    for (int m = 0; m < 8; m++) {
        #pragma unroll
        for (int r4 = 0; r4 < 4; r4++) {
            const int row = brow + wr * 128 + m * 16 + lhi * 4 + r4;
            const float s = rowScale[row] * wsc;
            #pragma unroll
            for (int n = 0; n < 4; n++) {
                const int col = bcol + wc * 64 + n * 16 + llo;
                float v = (float)acc[m][n][r4] * s + bias[col];
                if (GELU) {
                    float u = v + 0.044715f * v * v * v;
                    v = v / (1.0f + __expf(-1.5957691216057308f * u));
                }
                Cout[(size_t)row * Ncols + col] = v;
            }
        }
    }
}

// ---------------------------------------------------------------------------
extern "C" void kernel_launch(void* const* d_in, const int* in_sizes, int n_in,
                              void* d_out, int out_size, void* d_ws, size_t ws_size,
                              hipStream_t stream)
{
    const float* x  = (const float*)d_in[0];   // [8192,2048]
    const float* W1 = (const float*)d_in[1];   // [8192,2048]
    const float* B1 = (const float*)d_in[2];   // [8192]
    const float* W2 = (const float*)d_in[3];   // [2048,8192]
    const float* B2 = (const float*)d_in[4];   // [2048]
    float* out = (float*)d_out;                // [8192,2048]

    const int N = 8192, D = 2048, H = 8192;
    const size_t MB = 1024 * 1024;

    // 128KB dynamic LDS opt-in (host-side attribute set; not a stream op)
    hipFuncSetAttribute((const void*)gemm8_i8<1>,
                        hipFuncAttributeMaxDynamicSharedMemorySize, 131072);
    hipFuncSetAttribute((const void*)gemm8_i8<0>,
                        hipFuncAttributeMaxDynamicSharedMemorySize, 131072);

    // workspace layout (adaptive):
    //   0..64KB+: scales; 1MB: X1q 16MB (aliased by W2q later); 17MB: W1q 16MB;
    //   33MB: X2q 64MB; 97MB: X2f chunk staging (chunk*H*4 bytes)
    char* ws = (char*)d_ws;
    float* sW1 = (float*)(ws + 0);
    float* sW2 = (float*)(ws + 4);
    float* sX1 = (float*)(ws + 256);
    float* sX2 = (float*)(ws + 256 + 32768);
    size_t off = 1 * MB;
    int8_t* X1q = (int8_t*)(ws + off);
    int8_t* W2q = X1q;                 // alias: W2q written after X1q is dead
    off += (size_t)N * D;
    int8_t* W1q = (int8_t*)(ws + off); off += (size_t)H * D;
    int8_t* X2q = (int8_t*)(ws + off); off += (size_t)N * H;
    float*  X2f = (float*)(ws + off);
    const size_t fixedBytes = off;

    // largest chunk (multiple of 256 rows) whose f32 staging fits
    int chunk = N;
    if (ws_size < fixedBytes + (size_t)N * H * 4) {
        size_t avail = ws_size > fixedBytes ? ws_size - fixedBytes : 0;
        size_t c = avail / ((size_t)H * 4);
        c = (c / 256) * 256;
        if (c < 256) c = 256;
        if (c > (size_t)N) c = N;
        chunk = (int)c;
    }

    hipMemsetAsync(d_ws, 0, 256 + 65536, stream);

    wabs_kernel<<<2048, 256, 0, stream>>>(W1, H * D / 4, sW1);
    wquant_kernel<<<4096, 256, 0, stream>>>(W1, H * D / 4, sW1, (uint32_t*)W1q);
    rowquant_kernel<2><<<N, 256, 0, stream>>>(x, X1q, sX1);

    for (int r0 = 0; r0 < N; r0 += chunk) {
        const int rows = min(chunk, N - r0);
        gemm8_i8<1><<<(H / 256) * (rows / 256), 512, 131072, stream>>>(
            X1q + (size_t)r0 * D, W1q, D, H, H / 256,
            sX1 + r0, sW1, B1, X2f);
        rowquant_kernel<8><<<rows, 256, 0, stream>>>(
            X2f, X2q + (size_t)r0 * H, sX2 + r0);
    }

    wabs_kernel<<<2048, 256, 0, stream>>>(W2, D * H / 4, sW2);
    wquant_kernel<<<4096, 256, 0, stream>>>(W2, D * H / 4, sW2, (uint32_t*)W2q);

    gemm8_i8<0><<<(D / 256) * (N / 256), 512, 131072, stream>>>(
        X2q, W2q, H, D, D / 256, sX2, sW2, B2, out);
}